// Round 6
// baseline (488.065 us; speedup 1.0000x reference)
//
#include <hip/hip_runtime.h>
#include <hip/hip_cooperative_groups.h>

namespace cg = cooperative_groups;

#define N_NODES 8192
#define NODE_DIM 128
#define HIDDEN_DIM 256
#define CAP 96              // max raw entries/row; Poisson(16) -> P(>=96) ~ 1e-40
#define NBLOCKS 1024
#define ROWS_PER_BLOCK 8    // N_NODES / NBLOCKS

typedef __attribute__((ext_vector_type(8))) short bf16x8;
typedef __attribute__((ext_vector_type(4))) float f32x4;

static __device__ __forceinline__ unsigned short f2bf(float f) {
    unsigned u = __builtin_bit_cast(unsigned, f);
    unsigned r = u + 0x7fffu + ((u >> 16) & 1u);   // RNE
    return (unsigned short)(r >> 16);
}
static __device__ __forceinline__ float bf2f(unsigned short h) {
    unsigned u = ((unsigned)h) << 16;
    return __builtin_bit_cast(float, u);
}

// ---------------------------------------------------------------------------
// Single cooperative megakernel, 1024 blocks x 256 threads (4 blocks/CU):
//  P0: clear per-row raw counters; split W into bf16 hi/lo
//  P1: append ALL edges (duplicates included) to rowraw via atomicAdd
//  P2: per-row O(n^2) dedupe in LDS -> compacted cols stay in LDS; deg global
//  P3: aggregate y[i] = Dinv[i]*(Dinv[i]*x[i] + sum_j Dinv[j]*x[j]); split-bf16
//  P4: out = Yh*Wh + Yh*Wl + Yl*Wh via 16x16x32 bf16 MFMA (fp32-accurate)
// grid.sync() between phases provides execution + device-scope memory order.
// ---------------------------------------------------------------------------
__global__ __launch_bounds__(256, 4)
void mega_kernel(const int* __restrict__ e,
                 const float* __restrict__ x,
                 const float* __restrict__ W,
                 float* __restrict__ out,
                 unsigned int* __restrict__ cnt,
                 int* __restrict__ rowraw,
                 unsigned int* __restrict__ deg,
                 unsigned short* __restrict__ yh,
                 unsigned short* __restrict__ yl,
                 unsigned short* __restrict__ wh,
                 unsigned short* __restrict__ wl,
                 int E) {
    cg::grid_group grid = cg::this_grid();
    __shared__ int   cols_lds[ROWS_PER_BLOCK][CAP];  // compacted neighbor lists
    __shared__ float djs_lds[2][CAP];                // Dinv of neighbors (2 rows in flight)
    __shared__ int   ndist_lds[ROWS_PER_BLOCK];
    __shared__ int   lcnt[ROWS_PER_BLOCK];

    int tid = threadIdx.x;
    int b   = blockIdx.x;
    int gid = b * 256 + tid;

    // ---- P0: clear cnt (first 8192 threads); W -> bf16 hi/lo (next 8192) ----
    if (gid < N_NODES) cnt[gid] = 0u;
    int wq = gid - N_NODES;
    if (wq >= 0 && wq < HIDDEN_DIM * NODE_DIM / 4) {
        float4 v = ((const float4*)W)[wq];
        ushort4 h, l;
        h.x = f2bf(v.x); l.x = f2bf(v.x - bf2f(h.x));
        h.y = f2bf(v.y); l.y = f2bf(v.y - bf2f(h.y));
        h.z = f2bf(v.z); l.z = f2bf(v.z - bf2f(h.z));
        h.w = f2bf(v.w); l.w = f2bf(v.w - bf2f(h.w));
        ((ushort4*)wh)[wq] = h;
        ((ushort4*)wl)[wq] = l;
    }
    grid.sync();

    // ---- P1: append all edges (set-dedupe deferred to P2) ----
    if (gid < E) {
        int s = e[gid];        // row (src)
        int t = e[E + gid];    // col (tgt)
        unsigned int p = atomicAdd(&cnt[s], 1u);
        if (p < CAP) rowraw[(size_t)s * CAP + p] = t;
    }
    grid.sync();

    // ---- P2: per-row dedupe; 2 rows concurrently (128 threads each) ----
    int half = tid >> 7;
    int t128 = tid & 127;
    for (int iter = 0; iter < 4; ++iter) {
        int s = iter * 2 + half;
        int i = b * ROWS_PER_BLOCK + s;
        int n_raw = (int)cnt[i];
        if (n_raw > CAP) n_raw = CAP;
        int v = -1;
        if (t128 < n_raw) {
            v = rowraw[(size_t)i * CAP + t128];
            cols_lds[s][t128] = v;
        }
        __syncthreads();
        bool keep = (t128 < n_raw);
        if (keep) {
            for (int j = 0; j < t128; ++j)
                if (cols_lds[s][j] == v) { keep = false; break; }
        }
        __syncthreads();                       // all dup-check reads done
        if (t128 == 0) lcnt[s] = 0;
        __syncthreads();
        if (keep) {
            int pos = atomicAdd(&lcnt[s], 1);
            cols_lds[s][pos] = v;              // compact in place (reads finished)
        }
        __syncthreads();
        if (t128 == 0) { ndist_lds[s] = lcnt[s]; deg[i] = (unsigned int)lcnt[s]; }
    }
    grid.sync();

    // ---- P3: aggregate; self-edge in list + identity term -> A~[i][i]=2. OK ----
    for (int iter = 0; iter < 4; ++iter) {
        int s = iter * 2 + half;
        int i = b * ROWS_PER_BLOCK + s;
        int n = ndist_lds[s];
        if (t128 < n)
            djs_lds[half][t128] = rsqrtf((float)deg[cols_lds[s][t128]] + 1.0f);
        __syncthreads();
        float acc = 0.0f;
        for (int k = 0; k < n; ++k)
            acc += djs_lds[half][k] * x[(size_t)cols_lds[s][k] * NODE_DIM + t128];
        float di = rsqrtf((float)n + 1.0f);
        float val = di * (di * x[(size_t)i * NODE_DIM + t128] + acc);
        unsigned short h = f2bf(val);
        unsigned short l = f2bf(val - bf2f(h));
        yh[(size_t)i * NODE_DIM + t128] = h;
        yl[(size_t)i * NODE_DIM + t128] = l;
        __syncthreads();                       // before next iter reuses djs_lds
    }
    grid.sync();

    // ---- P4: GEMM out[8192,256] = Y @ W^T, split-bf16 MFMA ----
    // 1024 tiles of 64m x 32h, one per block; wave -> (m-half, h-half).
    {
        int wave = tid >> 6;
        int lane = tid & 63;
        int quad = lane >> 4;      // k-quad on inputs, row-quad on output
        int l16  = lane & 15;
        int m0   = (b >> 3) * 64 + (wave >> 1) * 32;
        int hcol = (b & 7) * 32 + (wave & 1) * 16 + l16;

        const unsigned short* wh_p = wh + (size_t)hcol * NODE_DIM + quad * 8;
        const unsigned short* wl_p = wl + (size_t)hcol * NODE_DIM + quad * 8;
        const unsigned short* yh_p = yh + (size_t)(m0 + l16) * NODE_DIM + quad * 8;
        const unsigned short* yl_p = yl + (size_t)(m0 + l16) * NODE_DIM + quad * 8;

        f32x4 acc[2] = {{0,0,0,0},{0,0,0,0}};
#pragma unroll
        for (int ks = 0; ks < 4; ++ks) {
            int k = ks * 32;
            bf16x8 bh = *(const bf16x8*)(wh_p + k);
            bf16x8 bl = *(const bf16x8*)(wl_p + k);
#pragma unroll
            for (int mt = 0; mt < 2; ++mt) {
                bf16x8 ah = *(const bf16x8*)(yh_p + k + mt * 16 * NODE_DIM);
                bf16x8 al = *(const bf16x8*)(yl_p + k + mt * 16 * NODE_DIM);
                acc[mt] = __builtin_amdgcn_mfma_f32_16x16x32_bf16(ah, bh, acc[mt], 0, 0, 0);
                acc[mt] = __builtin_amdgcn_mfma_f32_16x16x32_bf16(ah, bl, acc[mt], 0, 0, 0);
                acc[mt] = __builtin_amdgcn_mfma_f32_16x16x32_bf16(al, bh, acc[mt], 0, 0, 0);
            }
        }
#pragma unroll
        for (int mt = 0; mt < 2; ++mt)
#pragma unroll
            for (int r = 0; r < 4; ++r)
                out[(size_t)(m0 + mt * 16 + quad * 4 + r) * HIDDEN_DIM + hcol] = acc[mt][r];
    }
}

extern "C" void kernel_launch(void* const* d_in, const int* in_sizes, int n_in,
                              void* d_out, int out_size, void* d_ws, size_t ws_size,
                              hipStream_t stream) {
    const int*   e = (const int*)d_in[1];   // edge_index delivered as int32 [2, E]
    const float* x = (const float*)d_in[0];
    const float* W = (const float*)d_in[2];
    float*       out = (float*)d_out;
    int E = in_sizes[1] / 2;

    // ws layout: cnt 32KB | rowraw 3MB | deg 32KB | yh 2MB | yl 2MB | wh 64KB | wl 64KB
    unsigned int*   cnt    = (unsigned int*)d_ws;
    int*            rowraw = (int*)(cnt + N_NODES);
    unsigned int*   deg    = (unsigned int*)(rowraw + (size_t)N_NODES * CAP);
    unsigned short* yh     = (unsigned short*)(deg + N_NODES);
    unsigned short* yl     = yh + (size_t)N_NODES * NODE_DIM;
    unsigned short* wh     = yl + (size_t)N_NODES * NODE_DIM;
    unsigned short* wl     = wh + (size_t)HIDDEN_DIM * NODE_DIM;

    void* args[] = {(void*)&e, (void*)&x, (void*)&W, (void*)&out,
                    (void*)&cnt, (void*)&rowraw, (void*)&deg,
                    (void*)&yh, (void*)&yl, (void*)&wh, (void*)&wl, (void*)&E};
    hipLaunchCooperativeKernel((void*)mega_kernel, dim3(NBLOCKS), dim3(256),
                               args, 0, stream);
}

// Round 7
// 107.195 us; speedup vs baseline: 4.5531x; 4.5531x over previous
//
#include <hip/hip_runtime.h>

#define N_NODES 8192
#define NODE_DIM 128
#define HIDDEN_DIM 256
#define WORDS_PER_ROW 256   // 8192 bits / 32
#define CAP 96              // max distinct neighbors/row; Poisson(16) -> P(>=96) ~ 1e-40
#define MTILE 16            // rows aggregated + GEMMed per block
#define YPAD 136            // LDS row stride in ushorts (16B-aligned, breaks pow2 stride)

typedef __attribute__((ext_vector_type(8))) short bf16x8;
typedef __attribute__((ext_vector_type(4))) float f32x4;

static __device__ __forceinline__ unsigned short f2bf(float f) {
    unsigned u = __builtin_bit_cast(unsigned, f);
    unsigned r = u + 0x7fffu + ((u >> 16) & 1u);   // RNE
    return (unsigned short)(r >> 16);
}
static __device__ __forceinline__ float bf2f(unsigned short h) {
    unsigned u = ((unsigned)h) << 16;
    return __builtin_bit_cast(float, u);
}

// ---------------------------------------------------------------------------
// Kernel 1 (blocks < nEdgeBlocks): dedupe edges (set semantics) via N*N
// bitmask; append each NEW target to rowlist[s]; deg[s] = distinct count.
// Trailing 32 blocks: W -> split bf16 (Wh + Wl)  (independent work, fused to
// save a dispatch).
// ---------------------------------------------------------------------------
__global__ void dedupe_kernel(const int* __restrict__ e,
                              unsigned int* __restrict__ bitmask,
                              unsigned int* __restrict__ deg,
                              int* __restrict__ rowlist,
                              const float* __restrict__ W,
                              unsigned short* __restrict__ wh,
                              unsigned short* __restrict__ wl,
                              int E, int nEdgeBlocks) {
    if ((int)blockIdx.x < nEdgeBlocks) {
        int idx = blockIdx.x * 256 + threadIdx.x;
        if (idx >= E) return;
        int s = e[idx];        // row (src)
        int t = e[E + idx];    // col (tgt)
        unsigned int w = (unsigned int)s * WORDS_PER_ROW + ((unsigned int)t >> 5);
        unsigned int m = 1u << (t & 31);
        unsigned int old = atomicOr(&bitmask[w], m);
        if (!(old & m)) {
            unsigned int p = atomicAdd(&deg[s], 1u);
            if (p < CAP) rowlist[(size_t)s * CAP + p] = t;
        }
    } else {
        int t = (blockIdx.x - nEdgeBlocks) * 256 + threadIdx.x;  // float4 idx, 8192 total
        if (t >= HIDDEN_DIM * NODE_DIM / 4) return;
        float4 v = ((const float4*)W)[t];
        ushort4 h, l;
        h.x = f2bf(v.x); l.x = f2bf(v.x - bf2f(h.x));
        h.y = f2bf(v.y); l.y = f2bf(v.y - bf2f(h.y));
        h.z = f2bf(v.z); l.z = f2bf(v.z - bf2f(h.z));
        h.w = f2bf(v.w); l.w = f2bf(v.w - bf2f(h.w));
        ((ushort4*)wh)[t] = h;
        ((ushort4*)wl)[t] = l;
    }
}

// ---------------------------------------------------------------------------
// Kernel 2 (fused aggregate + GEMM), 512 blocks x 256 threads.
// Phase A: aggregate the block's 16 rows into LDS as split-bf16:
//   y[i] = Dinv[i]*(Dinv[i]*x[i] + sum_j Dinv[j]*x[cols_j])
//   (2 rows in parallel, 128 threads each; self-edge + identity -> A~[i][i]=2)
// Phase B: out[16x256 tile] = Y @ W^T via split-bf16 MFMA
//   out = Yh*Wh + Yh*Wl + Yl*Wh (fp32-accurate; Yl*Wl ~1e-5 rel, dropped).
//   A-frags (A[m=lane&15][k=quad*8+j]) read as one b128 from LDS;
//   C/D: col=lane&15 (h), row=quad*4+reg (m).
// No grid-wide sync needed: the out-tile reads only rows this block produced.
// ---------------------------------------------------------------------------
__global__ __launch_bounds__(256)
void fused_kernel(const int* __restrict__ rowlist,
                  const unsigned int* __restrict__ deg,
                  const float* __restrict__ x,
                  const unsigned short* __restrict__ wh,
                  const unsigned short* __restrict__ wl,
                  float* __restrict__ out) {
    __shared__ unsigned short yh_lds[MTILE][YPAD];
    __shared__ unsigned short yl_lds[MTILE][YPAD];
    __shared__ int   cols[2][CAP];
    __shared__ float djs[2][CAP];

    int tid  = threadIdx.x;
    int b    = blockIdx.x;
    int r0   = b * MTILE;
    int half = tid >> 7;
    int t128 = tid & 127;

    // ---- Phase A: aggregate 16 rows (8 iterations x 2 rows) ----
    for (int iter = 0; iter < MTILE / 2; ++iter) {
        int s = iter * 2 + half;
        int i = r0 + s;
        int n = (int)deg[i];
        if (n > CAP) n = CAP;
        if (t128 < n) {
            int c = rowlist[(size_t)i * CAP + t128];
            cols[half][t128] = c;
            djs[half][t128]  = rsqrtf((float)deg[c] + 1.0f);
        }
        __syncthreads();
        float acc = 0.0f;
        for (int k = 0; k < n; ++k)
            acc += djs[half][k] * x[(size_t)cols[half][k] * NODE_DIM + t128];
        float di  = rsqrtf((float)n + 1.0f);
        float val = di * (di * x[(size_t)i * NODE_DIM + t128] + acc);
        unsigned short h = f2bf(val);
        unsigned short l = f2bf(val - bf2f(h));
        yh_lds[s][t128] = h;
        yl_lds[s][t128] = l;
        __syncthreads();   // cols/djs buffers reused next iteration
    }

    // ---- Phase B: 16x256 out tile; wave w owns h-cols w*64..w*64+63 ----
    int wave = tid >> 6;
    int lane = tid & 63;
    int quad = lane >> 4;      // k-quad on inputs, m-row-quad on output
    int l16  = lane & 15;      // A m-row / B h-col / D col

    f32x4 acc4[4] = {{0,0,0,0},{0,0,0,0},{0,0,0,0},{0,0,0,0}};
#pragma unroll
    for (int ks = 0; ks < 4; ++ks) {
        int koff = ks * 32 + quad * 8;
        bf16x8 ah = *(const bf16x8*)&yh_lds[l16][koff];
        bf16x8 al = *(const bf16x8*)&yl_lds[l16][koff];
#pragma unroll
        for (int ht = 0; ht < 4; ++ht) {
            int hcol = wave * 64 + ht * 16 + l16;
            bf16x8 bh = *(const bf16x8*)(wh + (size_t)hcol * NODE_DIM + koff);
            bf16x8 bl = *(const bf16x8*)(wl + (size_t)hcol * NODE_DIM + koff);
            acc4[ht] = __builtin_amdgcn_mfma_f32_16x16x32_bf16(ah, bh, acc4[ht], 0, 0, 0);
            acc4[ht] = __builtin_amdgcn_mfma_f32_16x16x32_bf16(ah, bl, acc4[ht], 0, 0, 0);
            acc4[ht] = __builtin_amdgcn_mfma_f32_16x16x32_bf16(al, bh, acc4[ht], 0, 0, 0);
        }
    }

#pragma unroll
    for (int ht = 0; ht < 4; ++ht)
#pragma unroll
        for (int r = 0; r < 4; ++r)
            out[(size_t)(r0 + quad * 4 + r) * HIDDEN_DIM + wave * 64 + ht * 16 + l16] = acc4[ht][r];
}

extern "C" void kernel_launch(void* const* d_in, const int* in_sizes, int n_in,
                              void* d_out, int out_size, void* d_ws, size_t ws_size,
                              hipStream_t stream) {
    const float* x = (const float*)d_in[0];
    const int*   e = (const int*)d_in[1];   // edge_index delivered as int32 [2, E]
    const float* W = (const float*)d_in[2];
    float*       out = (float*)d_out;
    int E = in_sizes[1] / 2;

    // ws layout: bitmask 8MB | deg 32KB | rowlist 3MB | wh 64KB | wl 64KB
    unsigned int*   bitmask = (unsigned int*)d_ws;
    unsigned int*   deg     = bitmask + (size_t)N_NODES * WORDS_PER_ROW;
    int*            rowlist = (int*)(deg + N_NODES);
    unsigned short* wh      = (unsigned short*)(rowlist + (size_t)N_NODES * CAP);
    unsigned short* wl      = wh + (size_t)HIDDEN_DIM * NODE_DIM;

    // zero bitmask + deg (contiguous); rowlist needs no clear (guarded by deg)
    size_t clear_bytes = ((size_t)N_NODES * WORDS_PER_ROW + N_NODES) * sizeof(unsigned int);
    hipMemsetAsync(d_ws, 0, clear_bytes, stream);

    int nEdgeBlocks = (E + 255) / 256;
    int nWBlocks    = (HIDDEN_DIM * NODE_DIM / 4 + 255) / 256;   // 32
    dedupe_kernel<<<nEdgeBlocks + nWBlocks, 256, 0, stream>>>(e, bitmask, deg, rowlist,
                                                              W, wh, wl, E, nEdgeBlocks);
    fused_kernel<<<N_NODES / MTILE, 256, 0, stream>>>(rowlist, deg, x, wh, wl, out);
}

// Round 8
// 104.892 us; speedup vs baseline: 4.6530x; 1.0220x over previous
//
#include <hip/hip_runtime.h>

#define N_NODES 8192
#define NODE_DIM 128
#define HIDDEN_DIM 256
#define WORDS_PER_ROW 256   // 8192 bits / 32
#define CAP 96              // max distinct neighbors/row; Poisson(16) -> P(>=96) ~ 1e-40

typedef __attribute__((ext_vector_type(8))) short bf16x8;
typedef __attribute__((ext_vector_type(4))) float f32x4;

static __device__ __forceinline__ unsigned short f2bf(float f) {
    unsigned u = __builtin_bit_cast(unsigned, f);
    unsigned r = u + 0x7fffu + ((u >> 16) & 1u);   // RNE
    return (unsigned short)(r >> 16);
}
static __device__ __forceinline__ float bf2f(unsigned short h) {
    unsigned u = ((unsigned)h) << 16;
    return __builtin_bit_cast(float, u);
}

// ---------------------------------------------------------------------------
// Kernel 1 (blocks < nEdgeBlocks): dedupe edges (set semantics) via N*N
// bitmask; append each NEW target to rowlist[s]; deg[s] = distinct count.
// Trailing 32 blocks: W -> split bf16 (Wh + Wl), fused to save a dispatch.
// [R6/R7 lesson: dispatch boundaries are the cheapest sync on MI355X —
//  grid.sync() cost ~100 us/sync at 1024 blocks; intra-block agg+gemm fusion
//  serialized on barriers and lost 2.7 us. This 3-dispatch shape is the
//  measured optimum.]
// ---------------------------------------------------------------------------
__global__ void dedupe_kernel(const int* __restrict__ e,
                              unsigned int* __restrict__ bitmask,
                              unsigned int* __restrict__ deg,
                              int* __restrict__ rowlist,
                              const float* __restrict__ W,
                              unsigned short* __restrict__ wh,
                              unsigned short* __restrict__ wl,
                              int E, int nEdgeBlocks) {
    if ((int)blockIdx.x < nEdgeBlocks) {
        int idx = blockIdx.x * 256 + threadIdx.x;
        if (idx >= E) return;
        int s = e[idx];        // row (src)
        int t = e[E + idx];    // col (tgt)
        unsigned int w = (unsigned int)s * WORDS_PER_ROW + ((unsigned int)t >> 5);
        unsigned int m = 1u << (t & 31);
        unsigned int old = atomicOr(&bitmask[w], m);
        if (!(old & m)) {
            unsigned int p = atomicAdd(&deg[s], 1u);
            if (p < CAP) rowlist[(size_t)s * CAP + p] = t;
        }
    } else {
        int t = (blockIdx.x - nEdgeBlocks) * 256 + threadIdx.x;  // float4 idx, 8192 total
        if (t >= HIDDEN_DIM * NODE_DIM / 4) return;
        float4 v = ((const float4*)W)[t];
        ushort4 h, l;
        h.x = f2bf(v.x); l.x = f2bf(v.x - bf2f(h.x));
        h.y = f2bf(v.y); l.y = f2bf(v.y - bf2f(h.y));
        h.z = f2bf(v.z); l.z = f2bf(v.z - bf2f(h.z));
        h.w = f2bf(v.w); l.w = f2bf(v.w - bf2f(h.w));
        ((ushort4*)wh)[t] = h;
        ((ushort4*)wl)[t] = l;
    }
}

// ---------------------------------------------------------------------------
// Kernel 2: y[i] = Dinv[i]*(Dinv[i]*x[i] + sum_j Dinv[j]*x[cols_j]); split-bf16
// output.  One block per row (8192 blocks -> pure TLP, no serialization).
// Dinv[j] staged per-block in LDS (16 scattered 4B deg loads).  Two 128-thread
// groups split even/odd neighbors; one LDS exchange combines.
// Self-edge: j==i in list with dj==di, plus identity term -> A~[i][i]=2. OK.
// ---------------------------------------------------------------------------
__global__ __launch_bounds__(256)
void aggregate_kernel(const int* __restrict__ rowlist,
                      const unsigned int* __restrict__ deg,
                      const float* __restrict__ x,
                      unsigned short* __restrict__ yh,
                      unsigned short* __restrict__ yl) {
    __shared__ int   cols[CAP];
    __shared__ float djs[CAP];
    __shared__ float part[NODE_DIM];
    int i   = blockIdx.x;
    int tid = threadIdx.x;
    int n   = (int)deg[i];
    if (n > CAP) n = CAP;
    if (tid < n) {
        int c = rowlist[(size_t)i * CAP + tid];
        cols[tid] = c;
        djs[tid]  = rsqrtf((float)deg[c] + 1.0f);
    }
    __syncthreads();

    int g = tid >> 7;          // group 0/1
    int d = tid & 127;         // dim
    float acc = 0.0f;
    for (int k = g; k < n; k += 2) {
        acc += djs[k] * x[(size_t)cols[k] * NODE_DIM + d];
    }
    if (g == 0) part[d] = acc;
    __syncthreads();
    if (g == 1) {
        float di = rsqrtf((float)n + 1.0f);
        float v  = di * (di * x[(size_t)i * NODE_DIM + d] + part[d] + acc);
        unsigned short h = f2bf(v);
        unsigned short l = f2bf(v - bf2f(h));
        yh[(size_t)i * NODE_DIM + d] = h;
        yl[(size_t)i * NODE_DIM + d] = l;
    }
}

// ---------------------------------------------------------------------------
// Kernel 3: out[8192,256] = Y[8192,128] @ W[256,128]^T via split-bf16 MFMA:
// out = Yh*Wh + Yh*Wl + Yl*Wh  (fp32-accurate; Yl*Wl ~1e-5 rel, dropped).
// Block = 64 rows x 64 h; wave w owns 16 h across 4 row-tiles of 16.
// Frags (16x16x32_bf16: A[m=lane&15][k=quad*8+j]) load directly from
// L2-resident bf16 arrays; C/D: col=lane&15, row=quad*4+reg.
// ---------------------------------------------------------------------------
__global__ __launch_bounds__(256)
void gemm_kernel(const unsigned short* __restrict__ Yh,
                 const unsigned short* __restrict__ Yl,
                 const unsigned short* __restrict__ Wh,
                 const unsigned short* __restrict__ Wl,
                 float* __restrict__ out) {
    int tid  = threadIdx.x;
    int wave = tid >> 6;
    int lane = tid & 63;
    int quad = lane >> 4;       // k-quad on inputs, row-quad on output
    int l16  = lane & 15;       // A row within tile / B h within tile / C col
    int m0   = blockIdx.y * 64;
    int hcol = blockIdx.x * 64 + wave * 16 + l16;

    const unsigned short* wh_p = Wh + (size_t)hcol * NODE_DIM + quad * 8;
    const unsigned short* wl_p = Wl + (size_t)hcol * NODE_DIM + quad * 8;
    const unsigned short* yh_p = Yh + (size_t)(m0 + l16) * NODE_DIM + quad * 8;
    const unsigned short* yl_p = Yl + (size_t)(m0 + l16) * NODE_DIM + quad * 8;

    f32x4 acc[4] = {{0,0,0,0},{0,0,0,0},{0,0,0,0},{0,0,0,0}};
#pragma unroll
    for (int ks = 0; ks < 4; ++ks) {
        int k = ks * 32;
        bf16x8 bh = *(const bf16x8*)(wh_p + k);
        bf16x8 bl = *(const bf16x8*)(wl_p + k);
#pragma unroll
        for (int mt = 0; mt < 4; ++mt) {
            bf16x8 ah = *(const bf16x8*)(yh_p + k + mt * 16 * NODE_DIM);
            bf16x8 al = *(const bf16x8*)(yl_p + k + mt * 16 * NODE_DIM);
            acc[mt] = __builtin_amdgcn_mfma_f32_16x16x32_bf16(ah, bh, acc[mt], 0, 0, 0);
            acc[mt] = __builtin_amdgcn_mfma_f32_16x16x32_bf16(ah, bl, acc[mt], 0, 0, 0);
            acc[mt] = __builtin_amdgcn_mfma_f32_16x16x32_bf16(al, bh, acc[mt], 0, 0, 0);
        }
    }

#pragma unroll
    for (int mt = 0; mt < 4; ++mt) {
#pragma unroll
        for (int r = 0; r < 4; ++r) {
            out[(size_t)(m0 + mt * 16 + quad * 4 + r) * HIDDEN_DIM + hcol] = acc[mt][r];
        }
    }
}

extern "C" void kernel_launch(void* const* d_in, const int* in_sizes, int n_in,
                              void* d_out, int out_size, void* d_ws, size_t ws_size,
                              hipStream_t stream) {
    const float* x = (const float*)d_in[0];
    const int*   e = (const int*)d_in[1];   // edge_index delivered as int32 [2, E]
    const float* W = (const float*)d_in[2];
    float*       out = (float*)d_out;
    int E = in_sizes[1] / 2;

    // ws layout: bitmask 8MB | deg 32KB | rowlist 3MB | yh 2MB | yl 2MB | wh 64KB | wl 64KB
    unsigned int*   bitmask = (unsigned int*)d_ws;
    unsigned int*   deg     = bitmask + (size_t)N_NODES * WORDS_PER_ROW;
    int*            rowlist = (int*)(deg + N_NODES);
    unsigned short* yh      = (unsigned short*)(rowlist + (size_t)N_NODES * CAP);
    unsigned short* yl      = yh + (size_t)N_NODES * NODE_DIM;
    unsigned short* wh      = yl + (size_t)N_NODES * NODE_DIM;
    unsigned short* wl      = wh + (size_t)HIDDEN_DIM * NODE_DIM;

    // zero bitmask + deg (contiguous); rowlist needs no clear (guarded by deg)
    size_t clear_bytes = ((size_t)N_NODES * WORDS_PER_ROW + N_NODES) * sizeof(unsigned int);
    hipMemsetAsync(d_ws, 0, clear_bytes, stream);

    int nEdgeBlocks = (E + 255) / 256;
    int nWBlocks    = (HIDDEN_DIM * NODE_DIM / 4 + 255) / 256;   // 32
    dedupe_kernel<<<nEdgeBlocks + nWBlocks, 256, 0, stream>>>(e, bitmask, deg, rowlist,
                                                              W, wh, wl, E, nEdgeBlocks);
    aggregate_kernel<<<N_NODES, 256, 0, stream>>>(rowlist, deg, x, yh, yl);
    gemm_kernel<<<dim3(HIDDEN_DIM / 64, N_NODES / 64), 256, 0, stream>>>(yh, yl, wh, wl, out);
}